// Round 1
// baseline (1288.203 us; speedup 1.0000x reference)
//
#include <hip/hip_runtime.h>
#include <stdint.h>
#include <math.h>

#define NB      8
#define NPTS    16384
#define NPOINT  512
#define NCH     128
#define KNBR    32
#define R2      0.04f

typedef float v2f __attribute__((ext_vector_type(2)));

// CDNA packed fp32: 2 points per instruction. No FMA contraction possible,
// association preserved: (xx+yy)+zz, subtraction done as add of exact negation.
__device__ __forceinline__ v2f pk_add(v2f a, v2f b) {
    v2f d;
    asm("v_pk_add_f32 %0, %1, %2" : "=v"(d) : "v"(a), "v"(b));
    return d;
}
__device__ __forceinline__ v2f pk_mul(v2f a, v2f b) {
    v2f d;
    asm("v_pk_mul_f32 %0, %1, %2" : "=v"(d) : "v"(a), "v"(b));
    return d;
}

// argmax step over (value desc, index asc) using DPP permute (VALU latency)
#define DPP_ARG_STEP(v, p, CTRL) do {                                          \
    float _ov = __builtin_bit_cast(float, __builtin_amdgcn_update_dpp(         \
        __builtin_bit_cast(int, (v)), __builtin_bit_cast(int, (v)),            \
        (CTRL), 0xF, 0xF, false));                                             \
    int _op = __builtin_amdgcn_update_dpp((p), (p), (CTRL), 0xF, 0xF, false);  \
    bool _t = (_ov > (v)) || ((_ov == (v)) && (_op < (p)));                    \
    (v) = _t ? _ov : (v);                                                      \
    (p) = _t ? _op : (p);                                                      \
} while (0)

#define SHFL_ARG_STEP(v, p, XORAMT) do {                                       \
    float _ov = __shfl_xor((v), (XORAMT), 64);                                 \
    int   _op = __shfl_xor((p), (XORAMT), 64);                                 \
    bool _t = (_ov > (v)) || ((_ov == (v)) && (_op < (p)));                    \
    (v) = _t ? _ov : (v);                                                      \
    (p) = _t ? _op : (p);                                                      \
} while (0)

// -------- kernel 1: FPS (blocks 0..7) fused with feature transpose ----------
__global__
__attribute__((amdgpu_flat_work_group_size(1024, 1024)))
__attribute__((amdgpu_waves_per_eu(4, 4)))
void fps_transpose_kernel(const float* __restrict__ xyz,
                          const float* __restrict__ feat,
                          float* __restrict__ out,     // new_xyz at [0,12288)
                          int* __restrict__ cent,      // ws: 8*512 ints
                          float* __restrict__ ft,      // ws: (B,N,128) fp32
                          int use_ft)
{
    const int blk = blockIdx.x;
    const int tid = threadIdx.x;

    if (blk < NB) {
        const int b = blk;
        const float* xb = xyz + (size_t)b * NPTS * 3;
        // 16 points/thread as 8 packed pairs: pair j = global points
        // (2j)*1024+tid and (2j+1)*1024+tid
        v2f px[8], py[8], pz[8], dist[8];
#pragma unroll
        for (int j = 0; j < 8; ++j) {
            int p0 = (2 * j) * 1024 + tid;
            int p1 = p0 + 1024;
            px[j] = (v2f){xb[p0 * 3 + 0], xb[p1 * 3 + 0]};
            py[j] = (v2f){xb[p0 * 3 + 1], xb[p1 * 3 + 1]};
            pz[j] = (v2f){xb[p0 * 3 + 2], xb[p1 * 3 + 2]};
            dist[j] = (v2f){1e10f, 1e10f};
        }
        // parity double-buffered partials: single barrier per iteration is
        // sufficient (reads of buf p end before barrier A(i+1); next writes
        // to buf p happen only after the writer passes A(i+1)).
        __shared__ float s_v[2][16];
        __shared__ int   s_p[2][16];
        const int lane = tid & 63;
        const int wid  = tid >> 6;

        int   cur = 0;
        float cx = xb[0], cy = xb[1], cz = xb[2];
        if (tid == 0) {
            cent[b * NPOINT + 0] = 0;
            out[((size_t)b * NPOINT + 0) * 3 + 0] = cx;
            out[((size_t)b * NPOINT + 0) * 3 + 1] = cy;
            out[((size_t)b * NPOINT + 0) * 3 + 2] = cz;
        }

        for (int i = 1; i < NPOINT; ++i) {
            // exact negation -> pk_add(px, -cx) is bit-identical to px - cx
            v2f ncx = (v2f){-cx, -cx};
            v2f ncy = (v2f){-cy, -cy};
            v2f ncz = (v2f){-cz, -cz};
            float bv = -1.0f; int bk = 0;
#pragma unroll
            for (int j = 0; j < 8; ++j) {
                v2f dx = pk_add(px[j], ncx);
                v2f dy = pk_add(py[j], ncy);
                v2f dz = pk_add(pz[j], ncz);
                v2f s  = pk_add(pk_add(pk_mul(dx, dx), pk_mul(dy, dy)),
                                pk_mul(dz, dz));
                float nd0 = fminf(dist[j].x, s.x);   // np.minimum, exact
                float nd1 = fminf(dist[j].y, s.y);
                dist[j].x = nd0; dist[j].y = nd1;
                // pair winner: lower global index (nd0) wins ties
                float pv = fmaxf(nd0, nd1);
                int   pi = (nd1 > nd0) ? (2 * j + 1) : (2 * j);
                if (pv > bv) { bv = pv; bk = pi; }   // strict >: earliest wins
            }
            float rv = bv;
            int   rp = bk * 1024 + tid;  // global point index of local best
            // wave argmax: 4 DPP steps + 2 shuffles
            DPP_ARG_STEP(rv, rp, 0xB1);   // quad_perm(1,0,3,2)  xor 1
            DPP_ARG_STEP(rv, rp, 0x4E);   // quad_perm(2,3,0,1)  xor 2
            DPP_ARG_STEP(rv, rp, 0x141);  // row_half_mirror
            DPP_ARG_STEP(rv, rp, 0x140);  // row_mirror
            SHFL_ARG_STEP(rv, rp, 16);
            SHFL_ARG_STEP(rv, rp, 32);
            const int buf = i & 1;
            if (lane == 0) { s_v[buf][wid] = rv; s_p[buf][wid] = rp; }
            __syncthreads();   // single barrier: partials visible
            // all waves redundantly reduce the 16 partials (4 DPP steps)
            float fv = s_v[buf][lane & 15];
            int   fp = s_p[buf][lane & 15];
            DPP_ARG_STEP(fv, fp, 0xB1);
            DPP_ARG_STEP(fv, fp, 0x4E);
            DPP_ARG_STEP(fv, fp, 0x141);
            DPP_ARG_STEP(fv, fp, 0x140);
            cur = __builtin_amdgcn_readfirstlane(fp);
            // all threads fetch the new centroid coords from global (uniform
            // address -> scalar loads, L2-resident). Replaces barrier B + the
            // 16-way register publish switch.
            cx = xb[cur * 3 + 0];
            cy = xb[cur * 3 + 1];
            cz = xb[cur * 3 + 2];
            if (tid == 0) {
                cent[b * NPOINT + i] = cur;
                size_t o = ((size_t)b * NPOINT + i) * 3;
                out[o + 0] = cx; out[o + 1] = cy; out[o + 2] = cz;
            }
        }
    } else {
        if (!use_ft) return;
        // transpose feat (B,128,N) -> ft (B,N,128), 32x32 tiles, 1024 thr
        int t  = blk - NB;
        int b  = t >> 11;          // /2048 tiles per batch
        int r  = t & 2047;
        int ct = r >> 9;           // channel tile (4)
        int nt = r & 511;          // point tile (512)
        __shared__ float tile[32][33];
        int tx = tid & 31, ty = tid >> 5;
        int c = ct * 32 + ty, n = nt * 32 + tx;
        tile[ty][tx] = feat[((size_t)b * NCH + c) * NPTS + n];
        __syncthreads();
        int n2 = nt * 32 + ty, c2 = ct * 32 + tx;
        ft[((size_t)b * NPTS + n2) * NCH + c2] = tile[tx][ty];
    }
}

// -------- kernel 2: ball query + grouped max pool ---------------------------
__global__ __launch_bounds__(256, 4)
void query_pool_kernel(const float* __restrict__ xyz,
                       const float* __restrict__ feat,
                       const float* __restrict__ ft,
                       const int* __restrict__ cent,
                       float* __restrict__ out_sub,   // (B,128,512)
                       int use_ft)
{
    const int tid  = threadIdx.x;
    const int widx = tid >> 6;
    const int lane = tid & 63;
    const int w = blockIdx.x * 4 + widx;   // 0..4095
    const int b = w >> 9;
    const int s = w & 511;

    const float* xb = xyz + (size_t)b * NPTS * 3;
    const int ci = cent[b * NPOINT + s];
    const float sx = xb[ci * 3 + 0];
    const float sy = xb[ci * 3 + 1];
    const float sz = xb[ci * 3 + 2];
    const float snorm = __fadd_rn(__fadd_rn(__fmul_rn(sx, sx),
                                            __fmul_rn(sy, sy)),
                                  __fmul_rn(sz, sz));

    __shared__ int lidx[4][KNBR];
    int found = 0;
    for (int base = 0; base < NPTS && found < KNBR; base += 64) {
        int j = base + lane;
        float dx = xb[j * 3 + 0];
        float dy = xb[j * 3 + 1];
        float dz = xb[j * 3 + 2];
        float dn = __fadd_rn(__fadd_rn(__fmul_rn(dx, dx),
                                       __fmul_rn(dy, dy)),
                             __fmul_rn(dz, dz));
        float dot = __fadd_rn(__fadd_rn(__fmul_rn(sx, dx),
                                        __fmul_rn(sy, dy)),
                              __fmul_rn(sz, dz));
        // reference order: d = -2*dot; d += snorm; d += dnorm
        float d = __fadd_rn(__fadd_rn(__fmul_rn(-2.0f, dot), snorm), dn);
        bool inball = !(d > R2);
        unsigned long long mask = __ballot(inball);
        int before = (int)__popcll(mask & ((1ULL << lane) - 1ULL));
        int slot = found + before;
        if (inball && slot < KNBR) lidx[widx][slot] = j;
        found += (int)__popcll(mask);
    }
    int cnt = found < KNBR ? found : KNBR;   // cnt >= 1 (self in ball)
    __syncthreads();

    float a0 = -INFINITY, a1 = -INFINITY;
    if (use_ft) {
        for (int m = 0; m < cnt; ++m) {
            int i = lidx[widx][m];
            const float* row = ft + ((size_t)b * NPTS + i) * NCH;
            a0 = fmaxf(a0, row[lane]);
            a1 = fmaxf(a1, row[lane + 64]);
        }
    } else {
        for (int m = 0; m < cnt; ++m) {
            int i = lidx[widx][m];
            a0 = fmaxf(a0, feat[((size_t)b * NCH + lane) * NPTS + i]);
            a1 = fmaxf(a1, feat[((size_t)b * NCH + lane + 64) * NPTS + i]);
        }
    }
    out_sub[((size_t)b * NCH + lane) * NPOINT + s] = a0;
    out_sub[((size_t)b * NCH + lane + 64) * NPOINT + s] = a1;
}

extern "C" void kernel_launch(void* const* d_in, const int* in_sizes, int n_in,
                              void* d_out, int out_size, void* d_ws, size_t ws_size,
                              hipStream_t stream)
{
    const float* xyz  = (const float*)d_in[0];   // (8,16384,3)
    const float* feat = (const float*)d_in[1];   // (8,128,16384)
    float* out = (float*)d_out;                  // [new_xyz | sub_features]

    int*   cent = (int*)d_ws;                              // 16 KB
    float* ft   = (float*)((char*)d_ws + 16384);           // 67 MB transposed
    const size_t need_ft = 16384ull + (size_t)NB * NPTS * NCH * 4ull;
    int use_ft = (ws_size >= need_ft) ? 1 : 0;

    int nblocks1 = use_ft ? (NB + NB * (NCH / 32) * (NPTS / 32)) : NB;
    hipLaunchKernelGGL(fps_transpose_kernel, dim3(nblocks1), dim3(1024), 0, stream,
                       xyz, feat, out, cent, ft, use_ft);

    hipLaunchKernelGGL(query_pool_kernel, dim3((NB * NPOINT) / 4), dim3(256), 0, stream,
                       xyz, feat, ft, cent, out + (size_t)NB * NPOINT * 3, use_ft);
}

// Round 2
// 1181.986 us; speedup vs baseline: 1.0899x; 1.0899x over previous
//
#include <hip/hip_runtime.h>
#include <stdint.h>
#include <math.h>

#define NB      8
#define NPTS    16384
#define NPOINT  512
#define NCH     128
#define KNBR    32
#define R2      0.04f

typedef float v2f __attribute__((ext_vector_type(2)));

// argmax step over (value desc, index asc) using DPP permute (VALU latency)
#define DPP_ARG_STEP(v, p, CTRL) do {                                          \
    float _ov = __builtin_bit_cast(float, __builtin_amdgcn_update_dpp(         \
        __builtin_bit_cast(int, (v)), __builtin_bit_cast(int, (v)),            \
        (CTRL), 0xF, 0xF, false));                                             \
    int _op = __builtin_amdgcn_update_dpp((p), (p), (CTRL), 0xF, 0xF, false);  \
    bool _t = (_ov > (v)) || ((_ov == (v)) && (_op < (p)));                    \
    (v) = _t ? _ov : (v);                                                      \
    (p) = _t ? _op : (p);                                                      \
} while (0)

#define SHFL_ARG_STEP(v, p, XORAMT) do {                                       \
    float _ov = __shfl_xor((v), (XORAMT), 64);                                 \
    int   _op = __shfl_xor((p), (XORAMT), 64);                                 \
    bool _t = (_ov > (v)) || ((_ov == (v)) && (_op < (p)));                    \
    (v) = _t ? _ov : (v);                                                      \
    (p) = _t ? _op : (p);                                                      \
} while (0)

// -------- kernel 1: FPS (blocks 0..7) fused with feature transpose ----------
// Pin exactly 4 waves/EU (1 block of 16 waves per CU).
__global__
__attribute__((amdgpu_flat_work_group_size(1024, 1024)))
__attribute__((amdgpu_waves_per_eu(4, 4)))
void fps_transpose_kernel(const float* __restrict__ xyz,
                          const float* __restrict__ feat,
                          float* __restrict__ out,     // new_xyz at [0,12288)
                          int* __restrict__ cent,      // ws: 8*512 ints
                          float* __restrict__ ft,      // ws: (B,N,128) fp32
                          int use_ft)
{
    const int blk = blockIdx.x;
    const int tid = threadIdx.x;

    if (blk < NB) {
        const int b = blk;
        const float* xb = xyz + (size_t)b * NPTS * 3;
        // 16 points/thread, stored as 8 contiguous pairs so the compiler can
        // select v_pk_{add,mul}_f32 (VOP3P) for the distance math.
        // pair j: elem .x = point (2j)*1024+tid, elem .y = point (2j+1)*1024+tid
        v2f px[8], py[8], pz[8];
        float d[16];
#pragma unroll
        for (int j = 0; j < 8; ++j) {
            int p0 = (2 * j) * 1024 + tid;
            int p1 = p0 + 1024;
            px[j] = (v2f){xb[p0 * 3 + 0], xb[p1 * 3 + 0]};
            py[j] = (v2f){xb[p0 * 3 + 1], xb[p1 * 3 + 1]};
            pz[j] = (v2f){xb[p0 * 3 + 2], xb[p1 * 3 + 2]};
            d[2 * j] = 1e10f;
            d[2 * j + 1] = 1e10f;
        }
        __shared__ float s_v[16];
        __shared__ int   s_p[16];
        __shared__ float s_cx, s_cy, s_cz;
        const int lane = tid & 63;
        const int wid  = tid >> 6;

        if (tid == 0) {
            cent[b * NPOINT + 0] = 0;
            out[((size_t)b * NPOINT + 0) * 3 + 0] = xb[0];
            out[((size_t)b * NPOINT + 0) * 3 + 1] = xb[1];
            out[((size_t)b * NPOINT + 0) * 3 + 2] = xb[2];
            s_cx = xb[0]; s_cy = xb[1]; s_cz = xb[2];
        }
        __syncthreads();

        for (int i = 1; i < NPOINT; ++i) {
            const float cx = s_cx, cy = s_cy, cz = s_cz;
            const v2f cxv = (v2f){cx, cx};
            const v2f cyv = (v2f){cy, cy};
            const v2f czv = (v2f){cz, cz};
            // phase 1: update min-distances, track max VALUE only.
            float vmax = -1.0f;
#pragma unroll
            for (int j = 0; j < 8; ++j) {
                v2f s;
                {
#pragma clang fp contract(off)
                    // exact: vector sub/mul/add == per-element __fsub_rn etc.,
                    // association ((x2+y2)+z2) as in reference; pragma blocks
                    // v_pk_fma contraction.
                    v2f dx = px[j] - cxv;
                    v2f dy = py[j] - cyv;
                    v2f dz = pz[j] - czv;
                    s = dx * dx + dy * dy + dz * dz;
                }
                float nd0 = fminf(d[2 * j],     s.x);   // np.minimum, exact
                float nd1 = fminf(d[2 * j + 1], s.y);
                d[2 * j]     = nd0;
                d[2 * j + 1] = nd1;
                vmax = fmaxf(vmax, fmaxf(nd0, nd1));    // may fuse to v_max3
            }
            // phase 2: recover earliest k with d[k]==vmax (fmax returns one of
            // its operands, so a match is guaranteed; k descending scan makes
            // the smallest matching k win -> same tie-break as reference).
            int bk = 15;
#pragma unroll
            for (int k = 14; k >= 0; --k) bk = (d[k] == vmax) ? k : bk;

            float rv = vmax;
            int   rp = bk * 1024 + tid;  // global point index of local best
            // wave argmax: 4 DPP steps (VALU latency) + 2 shuffles
            DPP_ARG_STEP(rv, rp, 0xB1);   // quad_perm(1,0,3,2)  xor 1
            DPP_ARG_STEP(rv, rp, 0x4E);   // quad_perm(2,3,0,1)  xor 2
            DPP_ARG_STEP(rv, rp, 0x141);  // row_half_mirror     pairs 4-grps
            DPP_ARG_STEP(rv, rp, 0x140);  // row_mirror          pairs 8-grps
            SHFL_ARG_STEP(rv, rp, 16);
            SHFL_ARG_STEP(rv, rp, 32);
            if (lane == 0) { s_v[wid] = rv; s_p[wid] = rp; }
            __syncthreads();   // A: partials visible
            // all waves redundantly reduce the 16 partials (4 DPP steps)
            float fv = s_v[lane & 15];
            int   fp = s_p[lane & 15];
            DPP_ARG_STEP(fv, fp, 0xB1);
            DPP_ARG_STEP(fv, fp, 0x4E);
            DPP_ARG_STEP(fv, fp, 0x141);
            DPP_ARG_STEP(fv, fp, 0x140);
            const int cur = __builtin_amdgcn_readfirstlane(fp);
            if (tid == (cur & 1023)) {
                const int kk = cur >> 10;   // wave-uniform (SGPR) -> s_cbranch
                float ox = 0.f, oy = 0.f, oz = 0.f;
#define CASE_K(K) case K: ox = px[(K) >> 1][(K) & 1]; \
                          oy = py[(K) >> 1][(K) & 1]; \
                          oz = pz[(K) >> 1][(K) & 1]; break;
                switch (kk) {
                    CASE_K(0)  CASE_K(1)  CASE_K(2)  CASE_K(3)
                    CASE_K(4)  CASE_K(5)  CASE_K(6)  CASE_K(7)
                    CASE_K(8)  CASE_K(9)  CASE_K(10) CASE_K(11)
                    CASE_K(12) CASE_K(13) CASE_K(14) CASE_K(15)
                }
#undef CASE_K
                s_cx = ox; s_cy = oy; s_cz = oz;
                cent[b * NPOINT + i] = cur;
                size_t o = ((size_t)b * NPOINT + i) * 3;
                out[o + 0] = ox; out[o + 1] = oy; out[o + 2] = oz;
            }
            __syncthreads();   // B: new centroid coords visible
        }
    } else {
        if (!use_ft) return;
        // transpose feat (B,128,N) -> ft (B,N,128), 32x32 tiles, 1024 thr
        int t  = blk - NB;
        int b  = t >> 11;          // /2048 tiles per batch
        int r  = t & 2047;
        int ct = r >> 9;           // channel tile (4)
        int nt = r & 511;          // point tile (512)
        __shared__ float tile[32][33];
        int tx = tid & 31, ty = tid >> 5;
        int c = ct * 32 + ty, n = nt * 32 + tx;
        tile[ty][tx] = feat[((size_t)b * NCH + c) * NPTS + n];
        __syncthreads();
        int n2 = nt * 32 + ty, c2 = ct * 32 + tx;
        ft[((size_t)b * NPTS + n2) * NCH + c2] = tile[tx][ty];
    }
}

// -------- kernel 2: ball query + grouped max pool ---------------------------
__global__ __launch_bounds__(256, 4)
void query_pool_kernel(const float* __restrict__ xyz,
                       const float* __restrict__ feat,
                       const float* __restrict__ ft,
                       const int* __restrict__ cent,
                       float* __restrict__ out_sub,   // (B,128,512)
                       int use_ft)
{
    const int tid  = threadIdx.x;
    const int widx = tid >> 6;
    const int lane = tid & 63;
    const int w = blockIdx.x * 4 + widx;   // 0..4095
    const int b = w >> 9;
    const int s = w & 511;

    const float* xb = xyz + (size_t)b * NPTS * 3;
    const int ci = cent[b * NPOINT + s];
    const float sx = xb[ci * 3 + 0];
    const float sy = xb[ci * 3 + 1];
    const float sz = xb[ci * 3 + 2];
    const float snorm = __fadd_rn(__fadd_rn(__fmul_rn(sx, sx),
                                            __fmul_rn(sy, sy)),
                                  __fmul_rn(sz, sz));

    __shared__ int lidx[4][KNBR];
    int found = 0;
    for (int base = 0; base < NPTS && found < KNBR; base += 64) {
        int j = base + lane;
        float dx = xb[j * 3 + 0];
        float dy = xb[j * 3 + 1];
        float dz = xb[j * 3 + 2];
        float dn = __fadd_rn(__fadd_rn(__fmul_rn(dx, dx),
                                       __fmul_rn(dy, dy)),
                             __fmul_rn(dz, dz));
        float dot = __fadd_rn(__fadd_rn(__fmul_rn(sx, dx),
                                        __fmul_rn(sy, dy)),
                              __fmul_rn(sz, dz));
        // reference order: d = -2*dot; d += snorm; d += dnorm
        float d = __fadd_rn(__fadd_rn(__fmul_rn(-2.0f, dot), snorm), dn);
        bool inball = !(d > R2);
        unsigned long long mask = __ballot(inball);
        int before = (int)__popcll(mask & ((1ULL << lane) - 1ULL));
        int slot = found + before;
        if (inball && slot < KNBR) lidx[widx][slot] = j;
        found += (int)__popcll(mask);
    }
    int cnt = found < KNBR ? found : KNBR;   // cnt >= 1 (self in ball)
    __syncthreads();

    float a0 = -INFINITY, a1 = -INFINITY;
    if (use_ft) {
        for (int m = 0; m < cnt; ++m) {
            int i = lidx[widx][m];
            const float* row = ft + ((size_t)b * NPTS + i) * NCH;
            a0 = fmaxf(a0, row[lane]);
            a1 = fmaxf(a1, row[lane + 64]);
        }
    } else {
        for (int m = 0; m < cnt; ++m) {
            int i = lidx[widx][m];
            a0 = fmaxf(a0, feat[((size_t)b * NCH + lane) * NPTS + i]);
            a1 = fmaxf(a1, feat[((size_t)b * NCH + lane + 64) * NPTS + i]);
        }
    }
    out_sub[((size_t)b * NCH + lane) * NPOINT + s] = a0;
    out_sub[((size_t)b * NCH + lane + 64) * NPOINT + s] = a1;
}

extern "C" void kernel_launch(void* const* d_in, const int* in_sizes, int n_in,
                              void* d_out, int out_size, void* d_ws, size_t ws_size,
                              hipStream_t stream)
{
    const float* xyz  = (const float*)d_in[0];   // (8,16384,3)
    const float* feat = (const float*)d_in[1];   // (8,128,16384)
    float* out = (float*)d_out;                  // [new_xyz | sub_features]

    int*   cent = (int*)d_ws;                              // 16 KB
    float* ft   = (float*)((char*)d_ws + 16384);           // 67 MB transposed
    const size_t need_ft = 16384ull + (size_t)NB * NPTS * NCH * 4ull;
    int use_ft = (ws_size >= need_ft) ? 1 : 0;

    int nblocks1 = use_ft ? (NB + NB * (NCH / 32) * (NPTS / 32)) : NB;
    hipLaunchKernelGGL(fps_transpose_kernel, dim3(nblocks1), dim3(1024), 0, stream,
                       xyz, feat, out, cent, ft, use_ft);

    hipLaunchKernelGGL(query_pool_kernel, dim3((NB * NPOINT) / 4), dim3(256), 0, stream,
                       xyz, feat, ft, cent, out + (size_t)NB * NPOINT * 3, use_ft);
}